// Round 9
// baseline (88.796 us; speedup 1.0000x reference)
//
#include <hip/hip_runtime.h>

// Problem constants
#define B_    4
#define S_    2048
#define DM_   1024
#define DK_   64
#define SCALE_ 0.03125f   // 1024^-0.5  (reference scales by d_model^-0.5, not d_k)

typedef float        f32x4  __attribute__((ext_vector_type(4)));
typedef float        float8 __attribute__((ext_vector_type(8)));
typedef short        short8 __attribute__((ext_vector_type(8)));
typedef float        fltx4  __attribute__((ext_vector_type(4)));
typedef unsigned int uint2v __attribute__((ext_vector_type(2)));
typedef unsigned int uint4v __attribute__((ext_vector_type(4)));

// async global->LDS DMA, 16 B per lane. LDS dest is WAVE-UNIFORM base
// (hardware adds lane*16); global src is per-lane.
#define GLL16(gsrc, ldst)                                                   \
  __builtin_amdgcn_global_load_lds(                                         \
      (const __attribute__((address_space(1))) void*)(gsrc),                \
      (__attribute__((address_space(3))) void*)(ldst), 16, 0, 0)

// fp32 -> bf16, round-to-nearest-even
static __device__ __forceinline__ unsigned short f2bf(float f) {
  unsigned u = __float_as_uint(f);
  u += 0x7fffu + ((u >> 16) & 1u);
  return (unsigned short)(u >> 16);
}
static __device__ __forceinline__ uint2v pack4(float a, float b, float c, float d) {
  uint2v r;
  r.x = (unsigned)f2bf(a) | ((unsigned)f2bf(b) << 16);
  r.y = (unsigned)f2bf(c) | ((unsigned)f2bf(d) << 16);
  return r;
}

// ---------------------------------------------------------------------------
// Kernel 0: detect mask element width (int32 of {0,1} vs byte-packed bools).
// ---------------------------------------------------------------------------
__global__ void detect_kernel(const unsigned int* __restrict__ m, unsigned int* __restrict__ flag) {
  unsigned v = m[threadIdx.x];
  unsigned long long bad = __ballot(v > 1u);
  if (threadIdx.x == 0) flag[0] = (bad != 0ull) ? 1u : 0u;
}

// ---------------------------------------------------------------------------
// Kernel W: convert the 3 weight matrices to bf16 once. Wb: [which][64][1024].
// ---------------------------------------------------------------------------
__global__ __launch_bounds__(256) void wconv_kernel(
    const float* __restrict__ wq, const float* __restrict__ wk, const float* __restrict__ wv,
    unsigned short* __restrict__ Wb)
{
  const int idx   = blockIdx.x * 256 + threadIdx.x;
  const int which = idx >> 13;
  const int e     = idx & 8191;
  const float* __restrict__ w = (which == 0) ? wq : (which == 1) ? wk : wv;
  fltx4 v0 = *reinterpret_cast<const fltx4*>(w + (size_t)e * 8);
  fltx4 v1 = *reinterpret_cast<const fltx4*>(w + (size_t)e * 8 + 4);
  uint4v o;
  o.x = (unsigned)f2bf(v0.x) | ((unsigned)f2bf(v0.y) << 16);
  o.y = (unsigned)f2bf(v0.z) | ((unsigned)f2bf(v0.w) << 16);
  o.z = (unsigned)f2bf(v1.x) | ((unsigned)f2bf(v1.y) << 16);
  o.w = (unsigned)f2bf(v1.z) | ((unsigned)f2bf(v1.w) << 16);
  *reinterpret_cast<uint4v*>(Wb + (size_t)which * 65536 + (size_t)e * 8) = o;
}

// ---------------------------------------------------------------------------
// Kernel 1: pack mask to 1 bit/element (2 MB, L2-hot). Verified R2-T3.
// ---------------------------------------------------------------------------
__global__ __launch_bounds__(256) void maskpack_kernel(const unsigned char* __restrict__ mb,
                                                       const unsigned int* __restrict__ mi,
                                                       const unsigned int* __restrict__ flag,
                                                       unsigned int* __restrict__ mp) {
  const int w = blockIdx.x * 256 + threadIdx.x;
  unsigned out = 0;
  if (flag[0]) {
    const uint4v* p = reinterpret_cast<const uint4v*>(mb + (size_t)w * 32);
    uint4v a = p[0], b = p[1];
    unsigned ws0[8];
    ws0[0]=a.x; ws0[1]=a.y; ws0[2]=a.z; ws0[3]=a.w; ws0[4]=b.x; ws0[5]=b.y; ws0[6]=b.z; ws0[7]=b.w;
#pragma unroll
    for (int i = 0; i < 8; ++i) {
      unsigned v = ws0[i];
      out |= ((v & 0x000000ffu) ? 1u : 0u) << (i * 4 + 0);
      out |= ((v & 0x0000ff00u) ? 1u : 0u) << (i * 4 + 1);
      out |= ((v & 0x00ff0000u) ? 1u : 0u) << (i * 4 + 2);
      out |= ((v & 0xff000000u) ? 1u : 0u) << (i * 4 + 3);
    }
  } else {
    const uint4v* p = reinterpret_cast<const uint4v*>(mi + (size_t)w * 32);
#pragma unroll
    for (int i = 0; i < 8; ++i) {
      uint4v a = p[i];
      out |= (a.x ? 1u : 0u) << (i * 4 + 0);
      out |= (a.y ? 1u : 0u) << (i * 4 + 1);
      out |= (a.z ? 1u : 0u) << (i * 4 + 2);
      out |= (a.w ? 1u : 0u) << (i * 4 + 3);
    }
  }
  mp[w] = out;
}

// ---------------------------------------------------------------------------
// Kernel 2 (v7): staged projection, 16-row tiles for 6 blocks/CU.
// Sync structure = proj4/proj6 (verified: STAGE -> sync -> MFMA -> sync).
// Parameter changes only: 16-row x K=128 tiles, 128 threads (2 waves),
// LDS 24 KB (X 8 KB + W 16 KB) -> grid 512x3 = 1536 blocks = 6 blocks/CU
// (LDS cap exactly 6). Both waves share the 16 A-rows; wave wid computes
// output frags nf = {2*wid, 2*wid+1}. Same swizzle involution as proj6
// (verified 0 conflicts): global SOURCE pre-swizzled, reads XOR the same key.
// D[m=g*4+j][n=nfe*16+r16] (T1-verified fragment layout).
// ---------------------------------------------------------------------------
__global__ __launch_bounds__(128) void proj7_kernel(
    const float* __restrict__ xq, const float* __restrict__ xk, const float* __restrict__ xv,
    const unsigned short* __restrict__ Wb,
    unsigned short* __restrict__ Qp, unsigned short* __restrict__ Kp, unsigned short* __restrict__ Vt)
{
  const int which = blockIdx.y;
  const float* __restrict__ x = (which == 0) ? xq : (which == 1) ? xk : xv;
  const unsigned short* __restrict__ wsrc = Wb + (size_t)which * 65536;
  const int row0 = blockIdx.x * 16;
  const int tid = threadIdx.x, wid = tid >> 6;
  const int lane = tid & 63, g = lane >> 4, r16 = lane & 15;

  __shared__ __align__(16) float          XsF[2048];   // 16x128 f32 (swizzled content)
  __shared__ __align__(16) unsigned short WsH[8192];   // 64x128 bf16 (swizzled content)

  f32x4 acc[2];
#pragma unroll
  for (int i = 0; i < 2; ++i) { acc[i].x = 0.f; acc[i].y = 0.f; acc[i].z = 0.f; acc[i].w = 0.f; }

  // inverse-swizzled source coordinates for this thread's DMA slots
  int xrow[4], xcol[4], wrow[8], wcol[8];
#pragma unroll
  for (int i = 0; i < 4; ++i) {
    int L  = i * 2048 + tid * 16;             // linear LDS byte this DMA writes
    int Ux = L ^ (((L >> 9) & 15) << 4);      // X: row pitch 512 B (16 rows)
    xrow[i] = Ux >> 9;  xcol[i] = (Ux & 511) >> 2;
  }
#pragma unroll
  for (int i = 0; i < 8; ++i) {
    int L  = i * 2048 + tid * 16;
    int Uw = L ^ (((L >> 8) & 15) << 4);      // W: row pitch 256 B (64 rows)
    wrow[i] = Uw >> 8;  wcol[i] = (Uw & 255) >> 1;
  }

  for (int kb = 0; kb < 8; ++kb) {
    const int k0 = kb * 128;
    // stage X: 4 DMA slots (8 KB)
#pragma unroll
    for (int i = 0; i < 4; ++i)
      GLL16(x + (size_t)(row0 + xrow[i]) * DM_ + k0 + xcol[i],
            (char*)XsF + i * 2048 + wid * 1024);
    // stage W: 8 DMA slots (16 KB)
#pragma unroll
    for (int i = 0; i < 8; ++i)
      GLL16(wsrc + (size_t)wrow[i] * DM_ + k0 + wcol[i],
            (char*)WsH + i * 2048 + wid * 1024);
    __syncthreads();   // drains vmcnt(0): staged data visible (verified structure)

#pragma unroll
    for (int k2 = 0; k2 < 4; ++k2) {
      const int la  = r16 * 512 + k2 * 128 + g * 32;
      const int pa0 = la ^ (r16 << 4);
      const int pa1 = (la + 16) ^ (r16 << 4);
      fltx4 a0 = *reinterpret_cast<const fltx4*>((const char*)XsF + pa0);
      fltx4 a1 = *reinterpret_cast<const fltx4*>((const char*)XsF + pa1);
      short8 a;
      a[0] = (short)f2bf(a0.x); a[1] = (short)f2bf(a0.y);
      a[2] = (short)f2bf(a0.z); a[3] = (short)f2bf(a0.w);
      a[4] = (short)f2bf(a1.x); a[5] = (short)f2bf(a1.y);
      a[6] = (short)f2bf(a1.z); a[7] = (short)f2bf(a1.w);
#pragma unroll
      for (int nf = 0; nf < 2; ++nf) {
        const int nfe = wid * 2 + nf;
        const int lb = (nfe * 16 + r16) * 256 + k2 * 64 + g * 16;
        const int pb = lb ^ (r16 << 4);
        short8 b = *reinterpret_cast<const short8*>((const char*)WsH + pb);
        acc[nf] = __builtin_amdgcn_mfma_f32_16x16x32_bf16(a, b, acc[nf], 0, 0, 0);
      }
    }
    __syncthreads();   // all waves done reading before next stage overwrites
  }

  // store: row = row0 + g*4 + j, n = nfe*16 + r16
  if (which < 2) {
    unsigned short* __restrict__ dst = (which == 0) ? Qp : Kp;
#pragma unroll
    for (int nf = 0; nf < 2; ++nf) {
      const int nfe = wid * 2 + nf;
#pragma unroll
      for (int j = 0; j < 4; ++j)
        dst[(size_t)(row0 + g * 4 + j) * DK_ + nfe * 16 + r16] = f2bf(acc[nf][j]);
    }
  } else {
    const int grow = row0 + g * 4;
    const int bb = grow >> 11, sin = grow & 2047;
#pragma unroll
    for (int nf = 0; nf < 2; ++nf) {
      const int nfe = wid * 2 + nf;
      *reinterpret_cast<uint2v*>(Vt + (size_t)(bb * DK_ + nfe * 16 + r16) * S_ + sin) =
          pack4(acc[nf][0], acc[nf][1], acc[nf][2], acc[nf][3]);
    }
  }
}

// ---------------------------------------------------------------------------
// Kernel 3a: flash attention PARTIAL (split-S x4). Body verified R5/R6/R8.
// NEW (index-only): bijective XCD swizzle bxl = (bx&7)*256 + (bx>>3) so the
// 128 blocks sharing one (sp, b-pair) K/V slice land on one XCD -> K/V
// re-reads hit local L2 instead of L3. 2048 % 8 == 0 -> bijective (m204).
// ---------------------------------------------------------------------------
__global__ __launch_bounds__(64) void attn_part_kernel(
    const unsigned short* __restrict__ Qp, const unsigned short* __restrict__ Kp,
    const unsigned short* __restrict__ Vt, const unsigned int* __restrict__ mp,
    float* __restrict__ pacc, float* __restrict__ pm, float* __restrict__ pl)
{
  const int lane = threadIdx.x;
  const int g = lane >> 4, r16 = lane & 15;
  const int bx = blockIdx.x;
  const int bxl = (bx & 7) * 256 + (bx >> 3);   // XCD-locality remap (bijective)
  const int sp = bxl >> 9;
  const int qw = bxl & 511;
  const int b  = qw >> 7;
  const int q0 = (qw & 127) * 16;

  __shared__ __align__(16) unsigned short Kt[64][72];
  __shared__ __align__(16) unsigned short Vs[64][72];
  __shared__ __align__(16) unsigned short Pq[16][72];

  short8 aq0, aq1;
  {
    const unsigned short* qrow = Qp + (size_t)(b * S_ + q0 + r16) * DK_ + g * 8;
    aq0 = *reinterpret_cast<const short8*>(qrow);
    aq1 = *reinterpret_cast<const short8*>(qrow + 32);
  }

  float mrun[4], lsum[4], corr[4];
  f32x4 acc[4];
#pragma unroll
  for (int j = 0; j < 4; ++j) { mrun[j] = -3.0e38f; lsum[j] = 0.f; }
#pragma unroll
  for (int nf = 0; nf < 4; ++nf) { acc[nf].x = 0.f; acc[nf].y = 0.f; acc[nf].z = 0.f; acc[nf].w = 0.f; }

  const int srow_stage = lane >> 3, sgran = lane & 7;

  for (int st = sp * 8; st < sp * 8 + 8; ++st) {
    const int s0 = st * 64;
#pragma unroll
    for (int i = 0; i < 8; ++i) {
      int r = i * 8 + srow_stage;
      uint4v kv = *reinterpret_cast<const uint4v*>(Kp + (size_t)(b * S_ + s0 + r) * DK_ + sgran * 8);
      *reinterpret_cast<uint4v*>(&Kt[r][sgran * 8]) = kv;
      uint4v vv = *reinterpret_cast<const uint4v*>(Vt + (size_t)(b * DK_ + r) * S_ + s0 + sgran * 8);
      *reinterpret_cast<uint4v*>(&Vs[r][sgran * 8]) = vv;
    }
    unsigned long long mw[4];
#pragma unroll
    for (int j = 0; j < 4; ++j) {
      size_t widx = ((size_t)(b * S_ + q0 + g * 4 + j) * S_ + s0) >> 5;
      mw[j] = *reinterpret_cast<const unsigned long long*>(mp + widx);
    }
    __syncthreads();

    f32x4 sc[4];
#pragma unroll
    for (int nf = 0; nf < 4; ++nf) { sc[nf].x = 0.f; sc[nf].y = 0.f; sc[nf].z = 0.f; sc[nf].w = 0.f; }
#pragma unroll
    for (int nf = 0; nf < 4; ++nf) {
      short8 bk0 = *reinterpret_cast<const short8*>(&Kt[nf * 16 + r16][g * 8]);
      short8 bk1 = *reinterpret_cast<const short8*>(&Kt[nf * 16 + r16][32 + g * 8]);
      sc[nf] = __builtin_amdgcn_mfma_f32_16x16x32_bf16(aq0, bk0, sc[nf], 0, 0, 0);
      sc[nf] = __builtin_amdgcn_mfma_f32_16x16x32_bf16(aq1, bk1, sc[nf], 0, 0, 0);
    }
#pragma unroll
    for (int nf = 0; nf < 4; ++nf)
#pragma unroll
      for (int j = 0; j < 4; ++j) {
        float v = sc[nf][j] * SCALE_;
        sc[nf][j] = ((mw[j] >> (nf * 16 + r16)) & 1ull) ? 1e-9f : v;
      }
#pragma unroll
    for (int j = 0; j < 4; ++j) {
      float tm = fmaxf(fmaxf(sc[0][j], sc[1][j]), fmaxf(sc[2][j], sc[3][j]));
#pragma unroll
      for (int off = 1; off < 16; off <<= 1) tm = fmaxf(tm, __shfl_xor(tm, off));
      float mn = fmaxf(mrun[j], tm);
      corr[j] = __expf(mrun[j] - mn);
      mrun[j] = mn;
    }
#pragma unroll
    for (int nf = 0; nf < 4; ++nf)
#pragma unroll
      for (int j = 0; j < 4; ++j)
        sc[nf][j] = __expf(sc[nf][j] - mrun[j]);
#pragma unroll
    for (int j = 0; j < 4; ++j) {
      float rs = (sc[0][j] + sc[1][j]) + (sc[2][j] + sc[3][j]);
#pragma unroll
      for (int off = 1; off < 16; off <<= 1) rs += __shfl_xor(rs, off);
      lsum[j] = lsum[j] * corr[j] + rs;
    }
#pragma unroll
    for (int nf = 0; nf < 4; ++nf) {
      acc[nf].x *= corr[0]; acc[nf].y *= corr[1]; acc[nf].z *= corr[2]; acc[nf].w *= corr[3];
    }
#pragma unroll
    for (int nf = 0; nf < 4; ++nf)
#pragma unroll
      for (int j = 0; j < 4; ++j)
        Pq[g * 4 + j][nf * 16 + r16] = f2bf(sc[nf][j]);
    asm volatile("s_waitcnt lgkmcnt(0)" ::: "memory");

#pragma unroll
    for (int k2 = 0; k2 < 2; ++k2) {
      short8 pa = *reinterpret_cast<const short8*>(&Pq[r16][k2 * 32 + g * 8]);
#pragma unroll
      for (int nf = 0; nf < 4; ++nf) {
        short8 bv = *reinterpret_cast<const short8*>(&Vs[nf * 16 + r16][k2 * 32 + g * 8]);
        acc[nf] = __builtin_amdgcn_mfma_f32_16x16x32_bf16(pa, bv, acc[nf], 0, 0, 0);
      }
    }
    __syncthreads();
  }

  float* __restrict__ pa = pacc + (size_t)(sp * 512 + qw) * 1024;
#pragma unroll
  for (int nf = 0; nf < 4; ++nf)
#pragma unroll
    for (int j = 0; j < 4; ++j)
      pa[(g * 4 + j) * 64 + nf * 16 + r16] = acc[nf][j];
  if (r16 == 0) {
#pragma unroll
    for (int j = 0; j < 4; ++j) {
      pm[(sp * 512 + qw) * 16 + g * 4 + j] = mrun[j];
      pl[(sp * 512 + qw) * 16 + g * 4 + j] = lsum[j];
    }
  }
}

// ---------------------------------------------------------------------------
// Kernel 3b: merge 4 split partials. UNCHANGED (verified R5/R6/R8).
// ---------------------------------------------------------------------------
__global__ __launch_bounds__(64) void attn_merge_kernel(
    const float* __restrict__ pacc, const float* __restrict__ pm, const float* __restrict__ pl,
    float* __restrict__ out)
{
  const int qw = blockIdx.x;
  const int b = qw >> 7, q0 = (qw & 127) * 16;
  const int lane = threadIdx.x;

#pragma unroll 1
  for (int row = 0; row < 16; ++row) {
    float m0 = pm[(0 * 512 + qw) * 16 + row], m1 = pm[(1 * 512 + qw) * 16 + row];
    float m2 = pm[(2 * 512 + qw) * 16 + row], m3 = pm[(3 * 512 + qw) * 16 + row];
    float M = fmaxf(fmaxf(m0, m1), fmaxf(m2, m3));
    float w0 = __expf(m0 - M), w1 = __expf(m1 - M), w2 = __expf(m2 - M), w3 = __expf(m3 - M);
    float L = w0 * pl[(0 * 512 + qw) * 16 + row] + w1 * pl[(1 * 512 + qw) * 16 + row] +
              w2 * pl[(2 * 512 + qw) * 16 + row] + w3 * pl[(3 * 512 + qw) * 16 + row];
    float v = w0 * pacc[((size_t)(0 * 512 + qw) * 16 + row) * 64 + lane] +
              w1 * pacc[((size_t)(1 * 512 + qw) * 16 + row) * 64 + lane] +
              w2 * pacc[((size_t)(2 * 512 + qw) * 16 + row) * 64 + lane] +
              w3 * pacc[((size_t)(3 * 512 + qw) * 16 + row) * 64 + lane];
    out[(size_t)(b * S_ + q0 + row) * DK_ + lane] = v / L;
  }
}

// ---------------------------------------------------------------------------
// Kernel 3 (fallback if ws too small): verified single-pass attention.
// ---------------------------------------------------------------------------
__global__ __launch_bounds__(64) void attn_kernel(
    const unsigned short* __restrict__ Qp, const unsigned short* __restrict__ Kp,
    const unsigned short* __restrict__ Vt, const unsigned int* __restrict__ mp,
    float* __restrict__ out)
{
  const int lane = threadIdx.x;
  const int g = lane >> 4, r16 = lane & 15;
  const int qt = blockIdx.x & 127;
  const int b  = blockIdx.x >> 7;
  const int q0 = qt * 16;

  __shared__ __align__(16) unsigned short Kt[64][72];
  __shared__ __align__(16) unsigned short Vs[64][72];
  __shared__ __align__(16) unsigned short Pq[16][72];

  short8 aq0, aq1;
  {
    const unsigned short* qrow = Qp + (size_t)(b * S_ + q0 + r16) * DK_ + g * 8;
    aq0 = *reinterpret_cast<const short8*>(qrow);
    aq1 = *reinterpret_cast<const short8*>(qrow + 32);
  }

  float mrun[4], lsum[4], corr[4];
  f32x4 acc[4];
#pragma unroll
  for (int j = 0; j < 4; ++j) { mrun[j] = -3.0e38f; lsum[j] = 0.f; }
#pragma unroll
  for (int nf = 0; nf < 4; ++nf) { acc[nf].x = 0.f; acc[nf].y = 0.f; acc[nf].z = 0.f; acc[nf].w = 0.f; }

  const int srow_stage = lane >> 3, sgran = lane & 7;

  for (int st = 0; st < 32; ++st) {
    const int s0 = st * 64;
#pragma unroll
    for (int i = 0; i < 8; ++i) {
      int r = i * 8 + srow_stage;
      uint4v kv = *reinterpret_cast<const uint4v*>(Kp + (size_t)(b * S_ + s0 + r) * DK_ + sgran * 8);
      *reinterpret_cast<uint4v*>(&Kt[r][sgran * 8]) = kv;
      uint4v vv = *reinterpret_cast<const uint4v*>(Vt + (size_t)(b * DK_ + r) * S_ + s0 + sgran * 8);
      *reinterpret_cast<uint4v*>(&Vs[r][sgran * 8]) = vv;
    }
    unsigned long long mw[4];
#pragma unroll
    for (int j = 0; j < 4; ++j) {
      size_t widx = ((size_t)(b * S_ + q0 + g * 4 + j) * S_ + s0) >> 5;
      mw[j] = *reinterpret_cast<const unsigned long long*>(mp + widx);
    }
    __syncthreads();

    f32x4 sc[4];
#pragma unroll
    for (int nf = 0; nf < 4; ++nf) { sc[nf].x = 0.f; sc[nf].y = 0.f; sc[nf].z = 0.f; sc[nf].w = 0.f; }
#pragma unroll
    for (int nf = 0; nf < 4; ++nf) {
      short8 bk0 = *reinterpret_cast<const short8*>(&Kt[nf * 16 + r16][g * 8]);
      short8 bk1 = *reinterpret_cast<const short8*>(&Kt[nf * 16 + r16][32 + g * 8]);
      sc[nf] = __builtin_amdgcn_mfma_f32_16x16x32_bf16(aq0, bk0, sc[nf], 0, 0, 0);
      sc[nf] = __builtin_amdgcn_mfma_f32_16x16x32_bf16(aq1, bk1, sc[nf], 0, 0, 0);
    }
#pragma unroll
    for (int nf = 0; nf < 4; ++nf)
#pragma unroll
      for (int j = 0; j < 4; ++j) {
        float v = sc[nf][j] * SCALE_;
        sc[nf][j] = ((mw[j] >> (nf * 16 + r16)) & 1ull) ? 1e-9f : v;
      }
#pragma unroll
    for (int j = 0; j < 4; ++j) {
      float tm = fmaxf(fmaxf(sc[0][j], sc[1][j]), fmaxf(sc[2][j], sc[3][j]));
#pragma unroll
      for (int off = 1; off < 16; off <<= 1) tm = fmaxf(tm, __shfl_xor(tm, off));
      float mn = fmaxf(mrun[j], tm);
      corr[j] = __expf(mrun[j] - mn);
      mrun[j] = mn;
    }
#pragma unroll
    for (int nf = 0; nf < 4; ++nf)
#pragma unroll
      for (int j = 0; j < 4; ++j)
        sc[nf][j] = __expf(sc[nf][j] - mrun[j]);
#pragma unroll
    for (int j = 0; j < 4; ++j) {
      float rs = (sc[0][j] + sc[1][j]) + (sc[2][j] + sc[3][j]);
#pragma unroll
      for (int off = 1; off < 16; off <<= 1) rs += __shfl_xor(rs, off);
      lsum[j] = lsum[j] * corr[j] + rs;
    }
#pragma unroll
    for (int nf = 0; nf < 4; ++nf) {
      acc[nf].x *= corr[0]; acc[nf].y *= corr[1]; acc[nf].z *= corr[2]; acc[nf].w *= corr[3];
    }
#pragma unroll
    for (int nf = 0; nf < 4; ++nf)
#pragma unroll
      for (int j = 0; j < 4; ++j)
        Pq[g * 4 + j][nf * 16 + r16] = f2bf(sc[nf][j]);
    asm volatile("s_waitcnt lgkmcnt(0)" ::: "memory");

#pragma unroll
    for (int k2 = 0; k2 < 2; ++k2) {
      short8 pa = *reinterpret_cast<const short8*>(&Pq[r16][k2 * 32 + g * 8]);
#pragma unroll
      for (int nf = 0; nf < 4; ++nf) {
        short8 bv = *reinterpret_cast<const short8*>(&Vs[nf * 16 + r16][k2 * 32 + g * 8]);
        acc[nf] = __builtin_amdgcn_mfma_f32_16x16x32_bf16(pa, bv, acc[nf], 0, 0, 0);
      }
    }
    __syncthreads();
  }

#pragma unroll
  for (int nf = 0; nf < 4; ++nf)
#pragma unroll
    for (int j = 0; j < 4; ++j)
      out[(size_t)(b * S_ + q0 + g * 4 + j) * DK_ + nf * 16 + r16] = acc[nf][j] / lsum[j];
}

// ---------------------------------------------------------------------------
extern "C" void kernel_launch(void* const* d_in, const int* in_sizes, int n_in,
                              void* d_out, int out_size, void* d_ws, size_t ws_size,
                              hipStream_t stream) {
  const float* q  = (const float*)d_in[0];
  const float* k  = (const float*)d_in[1];
  const float* v  = (const float*)d_in[2];
  const void*  mk = d_in[3];
  const float* wq = (const float*)d_in[4];
  const float* wk = (const float*)d_in[5];
  const float* wv = (const float*)d_in[6];

  char* ws = (char*)d_ws;
  unsigned short* Qp   = (unsigned short*)(ws);                         // 1 MB
  unsigned short* Kp   = (unsigned short*)(ws + (1u << 20));            // 1 MB
  unsigned short* Vt   = (unsigned short*)(ws + (2u << 20));            // 1 MB  [b][dk][s]
  unsigned int*   mp   = (unsigned int*)  (ws + (3u << 20));            // 2 MB packed mask
  unsigned int*   flag = (unsigned int*)  (ws + (5u << 20));            // 4 B
  unsigned short* Wb   = (unsigned short*)(ws + (5u << 20) + 4096);     // 384 KB bf16 weights
  float*          pacc = (float*)(ws + (6u << 20));                     // 8 MB partial acc
  float*          pm   = (float*)(ws + (14u << 20));                    // 128 KB partial m
  float*          pl   = (float*)(ws + (14u << 20) + (1u << 17));       // 128 KB partial l

  wconv_kernel<<<96, 256, 0, stream>>>(wq, wk, wv, Wb);
  detect_kernel<<<1, 64, 0, stream>>>((const unsigned int*)mk, flag);
  maskpack_kernel<<<2048, 256, 0, stream>>>((const unsigned char*)mk, (const unsigned int*)mk, flag, mp);
  proj7_kernel<<<dim3(512, 3), 128, 0, stream>>>(q, k, v, Wb, Qp, Kp, Vt);

  if (ws_size >= (15u << 20)) {
    attn_part_kernel<<<2048, 64, 0, stream>>>(Qp, Kp, Vt, mp, pacc, pm, pl);
    attn_merge_kernel<<<512, 64, 0, stream>>>(pacc, pm, pl, (float*)d_out);
  } else {
    attn_kernel<<<512, 64, 0, stream>>>(Qp, Kp, Vt, mp, (float*)d_out);
  }
}